// Round 10
// baseline (553.749 us; speedup 1.0000x reference)
//
#include <hip/hip_runtime.h>

#define F_IN 256
#define EDIM 128
#define ALPHA 0.2f
#define SCAN_B 1024
#define BM 128
#define CHUNK 8192
#define BROWS 256   // rows per bucket; lrow packs in 8 bits above 17-bit col

typedef unsigned short u16;
typedef unsigned int u32;
typedef __bf16 bf16x8 __attribute__((ext_vector_type(8)));
typedef float f32x4 __attribute__((ext_vector_type(4)));

__device__ __forceinline__ float b2f(u16 b) {
    union { u32 u; float f; } v; v.u = ((u32)b) << 16; return v.f;
}
__device__ __forceinline__ u16 f2b(float f) {
    union { float f; u32 u; } v; v.f = f;
    u32 r = v.u + 0x7FFFu + ((v.u >> 16) & 1u);
    return (u16)(r >> 16);
}
__device__ __forceinline__ float unpack_lo(u32 g) {
    union { u32 u; float f; } v; v.u = g << 16; return v.f;
}
__device__ __forceinline__ float unpack_hi(u32 g) {
    union { u32 u; float f; } v; v.u = g & 0xFFFF0000u; return v.f;
}
__device__ __forceinline__ u32 pack2(float lo, float hi) {
    return ((u32)f2b(hi) << 16) | (u32)f2b(lo);
}

// ---------------- CSR build (no global row-atomics anywhere) ----------------

// One WG per 8192-edge chunk: LDS histogram over buckets -> chist[b][c].
__global__ __launch_bounds__(256) void k_chunk_hist(const int* __restrict__ erow,
                                                    int* __restrict__ chist,
                                                    int nE, int nbk, int nC) {
    extern __shared__ int histo[];
    const int c = blockIdx.x;
    const int t = threadIdx.x;
    for (int i = t; i < nbk; i += 256) histo[i] = 0;
    __syncthreads();
    const int beg = c * CHUNK;
    const int end = min(beg + CHUNK, nE);
    for (int e = beg + t; e < end; e += 256)
        atomicAdd(&histo[erow[e] >> 8], 1);
    __syncthreads();
    for (int i = t; i < nbk; i += 256)
        chist[(size_t)i * nC + c] = histo[i];
}

// One WG per bucket: exclusive scan of its nC chunk-counts; total -> bsum2.
__global__ void k_scan_chunks(int* __restrict__ chist, int* __restrict__ bsum2, int nC) {
    __shared__ int s[SCAN_B];
    const int b = blockIdx.x;
    int t = threadIdx.x;
    int v = (t < nC) ? chist[(size_t)b * nC + t] : 0;
    s[t] = v;
    __syncthreads();
    for (int d = 1; d < SCAN_B; d <<= 1) {
        int add = (t >= d) ? s[t - d] : 0;
        __syncthreads();
        s[t] += add;
        __syncthreads();
    }
    if (t < nC) chist[(size_t)b * nC + t] = s[t] - v;
    if (t == SCAN_B - 1) bsum2[b] = s[t];
}

// Scan bucket totals: boff2 = exclusive, boff2[nbk] = nE.
__global__ void k_scan_bsums(const int* __restrict__ bsum, int* __restrict__ boff, int nb) {
    __shared__ int s[SCAN_B];
    int t = threadIdx.x;
    int v = (t < nb) ? bsum[t] : 0;
    s[t] = v;
    __syncthreads();
    for (int d = 1; d < SCAN_B; d <<= 1) {
        int add = (t >= d) ? s[t - d] : 0;
        __syncthreads();
        s[t] += add;
        __syncthreads();
    }
    if (t < nb) boff[t] = s[t] - v;
    if (t == SCAN_B - 1) boff[nb] = s[t];
}

__global__ void k_add_off2(int* __restrict__ chist, const int* __restrict__ boff2, int nC) {
    const int b = blockIdx.x;
    int t = threadIdx.x;
    if (t < nC) chist[(size_t)b * nC + t] += boff2[b];
}

// One WG per chunk: claim via LDS cursors (seeded from chist), write each
// bucket's edges contiguously into its reserved sub-range.
__global__ __launch_bounds__(256) void k_scatter2(const int* __restrict__ erow,
                                                  const int* __restrict__ ecol,
                                                  const float* __restrict__ eval,
                                                  const int* __restrict__ chist,
                                                  int2* __restrict__ ebuf,
                                                  int nE, int nbk, int nC) {
    extern __shared__ int cur[];
    const int c = blockIdx.x;
    const int t = threadIdx.x;
    for (int i = t; i < nbk; i += 256) cur[i] = chist[(size_t)i * nC + c];
    __syncthreads();
    const int beg = c * CHUNK;
    const int end = min(beg + CHUNK, nE);
    for (int e = beg + t; e < end; e += 256) {
        int r = erow[e];
        int pos = atomicAdd(&cur[r >> 8], 1);
        ebuf[pos] = make_int2(ecol[e] | ((r & (BROWS - 1)) << 17), __float_as_int(eval[e]));
    }
}

// One WG per bucket: LDS row-histogram + scan -> rowptr (coalesced write),
// then cursor-claim pass writes final CSR inside the L2-resident window.
// Last block also zero-pads edges[nE..nE+15] for the SpMM batch loop.
__global__ __launch_bounds__(256) void k_local_sort2(const int* __restrict__ boff2,
                                                     const int2* __restrict__ ebuf,
                                                     int2* __restrict__ edges,
                                                     int* __restrict__ rowptr,
                                                     int n, int nbk) {
    __shared__ int hist[BROWS];
    __shared__ int s[BROWS];
    const int b = blockIdx.x;
    const int r0 = b * BROWS;
    const int t = threadIdx.x;
    const int beg = boff2[b];
    const int end = boff2[b + 1];
    hist[t] = 0;
    __syncthreads();
    for (int j = beg + t; j < end; j += 256)
        atomicAdd(&hist[(ebuf[j].x >> 17) & (BROWS - 1)], 1);
    __syncthreads();
    int v = hist[t];
    s[t] = v;
    __syncthreads();
    #pragma unroll
    for (int d = 1; d < BROWS; d <<= 1) {
        int add = (t >= d) ? s[t - d] : 0;
        __syncthreads();
        s[t] += add;
        __syncthreads();
    }
    int excl = beg + s[t] - v;
    if (r0 + t < n) rowptr[r0 + t] = excl;
    if (b == nbk - 1 && t == 255) rowptr[n] = end;   // rowptr[n] = nE
    if (b == nbk - 1 && t < 16) edges[end + t] = make_int2(0, 0);  // pad
    hist[t] = excl;                                   // reuse as cursor
    __syncthreads();
    for (int j = beg + t; j < end; j += 256) {
        int2 e = ebuf[j];
        int lrow = (e.x >> 17) & (BROWS - 1);
        int pos = atomicAdd(&hist[lrow], 1);
        edges[pos] = make_int2(e.x & 0x1FFFF, e.y);
    }
}

// ---------------- weight prep ----------------

__global__ void k_prep(const float* __restrict__ W, const float* __restrict__ catW,
                       u16* __restrict__ Wb, u16* __restrict__ catWb) {
    int idx = blockIdx.x * 256 + threadIdx.x;
    if (idx < F_IN * EDIM) {
        int k = idx >> 7;
        int c = idx & 127;
        Wb[c * F_IN + k] = f2b(W[idx]);
    } else {
        int j = idx - F_IN * EDIM;
        if (j < EDIM * 2 * EDIM) catWb[j] = f2b(catW[j]);
    }
}

// ---------------- MFMA GEMMs ----------------

#define LSTRIDE 40

__global__ __launch_bounds__(256) void k_gemm1_relu(const float* __restrict__ feature,
                                                    const u16* __restrict__ Wb,
                                                    u16* __restrict__ supb, int n) {
    __shared__ __align__(16) u16 As[BM][LSTRIDE];
    __shared__ __align__(16) u16 Bs[EDIM][LSTRIDE];
    const int t = threadIdx.x;
    const int r0 = blockIdx.x * BM;
    const int w = t >> 6, lane = t & 63;
    const int wr = w >> 1, wc = w & 1;
    const int lm = lane & 15, kg = lane >> 4;

    f32x4 acc[4][4];
    #pragma unroll
    for (int m = 0; m < 4; ++m)
        #pragma unroll
        for (int nn = 0; nn < 4; ++nn)
            acc[m][nn] = (f32x4){0.f, 0.f, 0.f, 0.f};

    const int srow = t >> 1;
    const int koff = (t & 1) * 16;

    for (int kt = 0; kt < F_IN / 32; ++kt) {
        const int k0 = kt * 32;
        {
            u32 pk[8];
            if (r0 + srow < n) {
                const float* src = feature + (size_t)(r0 + srow) * F_IN + k0 + koff;
                #pragma unroll
                for (int q = 0; q < 4; ++q) {
                    float4 f = *reinterpret_cast<const float4*>(src + q * 4);
                    pk[q * 2 + 0] = pack2(f.x, f.y);
                    pk[q * 2 + 1] = pack2(f.z, f.w);
                }
            } else {
                #pragma unroll
                for (int q = 0; q < 8; ++q) pk[q] = 0;
            }
            uint4* dst = reinterpret_cast<uint4*>(&As[srow][koff]);
            dst[0] = make_uint4(pk[0], pk[1], pk[2], pk[3]);
            dst[1] = make_uint4(pk[4], pk[5], pk[6], pk[7]);
        }
        {
            const uint4* src = reinterpret_cast<const uint4*>(Wb + (size_t)srow * F_IN + k0 + koff);
            uint4* dst = reinterpret_cast<uint4*>(&Bs[srow][koff]);
            dst[0] = src[0];
            dst[1] = src[1];
        }
        __syncthreads();
        #pragma unroll
        for (int m = 0; m < 4; ++m) {
            bf16x8 a = *reinterpret_cast<const bf16x8*>(&As[wr * 64 + m * 16 + lm][kg * 8]);
            #pragma unroll
            for (int nn = 0; nn < 4; ++nn) {
                bf16x8 b = *reinterpret_cast<const bf16x8*>(&Bs[wc * 64 + nn * 16 + lm][kg * 8]);
                acc[m][nn] = __builtin_amdgcn_mfma_f32_16x16x32_bf16(a, b, acc[m][nn], 0, 0, 0);
            }
        }
        __syncthreads();
    }
    #pragma unroll
    for (int m = 0; m < 4; ++m) {
        #pragma unroll
        for (int r = 0; r < 4; ++r) {
            int row = r0 + wr * 64 + m * 16 + kg * 4 + r;
            if (row >= n) continue;
            u16* dst = supb + (size_t)row * EDIM;
            #pragma unroll
            for (int nn = 0; nn < 4; ++nn) {
                int col = wc * 64 + nn * 16 + lm;
                dst[col] = f2b(fmaxf(acc[m][nn][r], 0.f));
            }
        }
    }
}

__global__ __launch_bounds__(256) void k_final(const u16* __restrict__ supb,
                                               const u16* __restrict__ s1b,
                                               const u16* __restrict__ s2b,
                                               float* __restrict__ out,
                                               const u16* __restrict__ catWb,
                                               const float* __restrict__ catb,
                                               const float* __restrict__ bvec, int n) {
    __shared__ __align__(16) u16 As[BM][LSTRIDE];
    __shared__ __align__(16) u16 Bs[EDIM][LSTRIDE];
    const int t = threadIdx.x;
    const int r0 = blockIdx.x * BM;
    const int w = t >> 6, lane = t & 63;
    const int wr = w >> 1, wc = w & 1;
    const int lm = lane & 15, kg = lane >> 4;

    f32x4 acc[4][4];
    #pragma unroll
    for (int m = 0; m < 4; ++m)
        #pragma unroll
        for (int nn = 0; nn < 4; ++nn)
            acc[m][nn] = (f32x4){0.f, 0.f, 0.f, 0.f};

    const int srow = t >> 1;
    const int koff = (t & 1) * 16;

    for (int kt = 0; kt < (2 * EDIM) / 32; ++kt) {
        const int k0 = kt * 32;
        {
            u32 pk[8];
            if (r0 + srow < n) {
                const int kk = k0 + koff;
                const int lo = (kk < EDIM);
                const int kcol = lo ? kk : kk - EDIM;
                size_t off = (size_t)(r0 + srow) * EDIM + kcol;
                const uint4* pa = reinterpret_cast<const uint4*>((lo ? s1b : s2b) + off);
                const uint4* pq = reinterpret_cast<const uint4*>(supb + off);
                uint4 a0 = pa[0], a1 = pa[1];
                uint4 q0 = pq[0], q1 = pq[1];
                const u32 av[8] = {a0.x, a0.y, a0.z, a0.w, a1.x, a1.y, a1.z, a1.w};
                const u32 qv[8] = {q0.x, q0.y, q0.z, q0.w, q1.x, q1.y, q1.z, q1.w};
                const float sgn = lo ? 1.f : -1.f;
                #pragma unroll
                for (int q = 0; q < 8; ++q) {
                    float x = unpack_lo(av[q]) + sgn * unpack_lo(qv[q]);
                    float y = unpack_hi(av[q]) + sgn * unpack_hi(qv[q]);
                    pk[q] = pack2(x, y);
                }
            } else {
                #pragma unroll
                for (int q = 0; q < 8; ++q) pk[q] = 0;
            }
            uint4* dst = reinterpret_cast<uint4*>(&As[srow][koff]);
            dst[0] = make_uint4(pk[0], pk[1], pk[2], pk[3]);
            dst[1] = make_uint4(pk[4], pk[5], pk[6], pk[7]);
        }
        {
            const uint4* src = reinterpret_cast<const uint4*>(catWb + (size_t)srow * (2 * EDIM) + k0 + koff);
            uint4* dst = reinterpret_cast<uint4*>(&Bs[srow][koff]);
            dst[0] = src[0];
            dst[1] = src[1];
        }
        __syncthreads();
        #pragma unroll
        for (int m = 0; m < 4; ++m) {
            bf16x8 a = *reinterpret_cast<const bf16x8*>(&As[wr * 64 + m * 16 + lm][kg * 8]);
            #pragma unroll
            for (int nn = 0; nn < 4; ++nn) {
                bf16x8 b = *reinterpret_cast<const bf16x8*>(&Bs[wc * 64 + nn * 16 + lm][kg * 8]);
                acc[m][nn] = __builtin_amdgcn_mfma_f32_16x16x32_bf16(a, b, acc[m][nn], 0, 0, 0);
            }
        }
        __syncthreads();
    }
    #pragma unroll
    for (int nn = 0; nn < 4; ++nn) {
        int col = wc * 64 + nn * 16 + lm;
        float cbv = catb[col];
        float bbv = bvec[col];
        #pragma unroll
        for (int m = 0; m < 4; ++m) {
            #pragma unroll
            for (int r = 0; r < 4; ++r) {
                int row = r0 + wr * 64 + m * 16 + kg * 4 + r;
                if (row >= n) continue;
                float v = acc[m][nn][r] + cbv;
                v = (v > 0.f ? v : ALPHA * v) + bbv;
                out[(size_t)row * EDIM + col] = v;
            }
        }
    }
}

// y(bf16) = A @ x(bf16): 2 waves per dest row (64 cols each, 2B/lane),
// masked batches of 16 -> 16 gathers in flight, no scalar tail.
__global__ __launch_bounds__(256) void k_spmm_csr(const int* __restrict__ rowptr,
                                                  const int2* __restrict__ edges,
                                                  const u16* __restrict__ xb,
                                                  u16* __restrict__ yb, int n) {
    const int w = threadIdx.x >> 6;
    const int lane = threadIdx.x & 63;
    const int row = blockIdx.x * 2 + (w >> 1);
    if (row >= n) return;
    const int c = (w & 1) * 64 + lane;
    const int beg = rowptr[row];
    const int end = rowptr[row + 1];
    float acc = 0.f;
    for (int j = beg; j < end; j += 16) {
        int   cc[16];
        float vv[16];
        #pragma unroll
        for (int q = 0; q < 16; ++q) {
            int2 e = edges[j + q];             // safe: edges padded +16
            cc[q] = e.x;
            vv[q] = (j + q < end) ? __int_as_float(e.y) : 0.f;
        }
        float xv[16];
        #pragma unroll
        for (int q = 0; q < 16; ++q)
            xv[q] = b2f(xb[(size_t)cc[q] * EDIM + c]);
        #pragma unroll
        for (int q = 0; q < 16; ++q)
            acc = fmaf(vv[q], xv[q], acc);
    }
    yb[(size_t)row * EDIM + c] = f2b(acc);
}

extern "C" void kernel_launch(void* const* d_in, const int* in_sizes, int n_in,
                              void* d_out, int out_size, void* d_ws, size_t ws_size,
                              hipStream_t stream) {
    const float* feature = (const float*)d_in[0];
    const int*   erow    = (const int*)d_in[1];
    const int*   ecol    = (const int*)d_in[2];
    const float* eval    = (const float*)d_in[3];
    const float* W       = (const float*)d_in[4];
    const float* b       = (const float*)d_in[5];
    const float* catW    = (const float*)d_in[6];
    const float* catb    = (const float*)d_in[7];
    float* out = (float*)d_out;

    const int n  = in_sizes[0] / F_IN;
    const int nE = in_sizes[1];
    const int nbk = (n + BROWS - 1) / BROWS;        // buckets (<=1024)
    const int nC  = (nE + CHUNK - 1) / CHUNK;       // chunks  (<=1024)

    char* p = (char*)d_ws;
    u16*  supb = (u16*)p;                   p += (size_t)n * EDIM * sizeof(u16);
    u16*  s1b  = (u16*)p;                   p += (size_t)n * EDIM * sizeof(u16);
    u16*  s2b  = (u16*)p;                   p += (size_t)n * EDIM * sizeof(u16);
    p = (char*)(((size_t)p + 15) & ~(size_t)15);
    u16*  Wb   = (u16*)p;                   p += (size_t)F_IN * EDIM * sizeof(u16);
    u16*  catWb = (u16*)p;                  p += (size_t)EDIM * 2 * EDIM * sizeof(u16);
    p = (char*)(((size_t)p + 15) & ~(size_t)15);
    int2* edges = (int2*)p;                 p += (size_t)(nE + 16) * sizeof(int2);
    int2* ebuf  = (int2*)p;                 p += (size_t)nE * sizeof(int2);
    int*  rowptr = (int*)p;                 p += (size_t)(n + 1) * sizeof(int);
    int*  chist  = (int*)p;                 p += (size_t)nbk * nC * sizeof(int);
    int*  bsum2  = (int*)p;                 p += (size_t)nbk * sizeof(int);
    int*  boff2  = (int*)p;                 p += (size_t)(nbk + 1) * sizeof(int);

    const int gemmBlocks = (n + BM - 1) / BM;
    const int spmmBlocks = (n + 1) / 2;
    const size_t ldsHist = (size_t)nbk * sizeof(int);

    // ---- chunk x bucket reservation (atomic-free global ordering) ----
    k_chunk_hist<<<nC, 256, ldsHist, stream>>>(erow, chist, nE, nbk, nC);
    k_scan_chunks<<<nbk, SCAN_B, 0, stream>>>(chist, bsum2, nC);
    k_scan_bsums<<<1, SCAN_B, 0, stream>>>(bsum2, boff2, nbk);
    k_add_off2<<<nbk, SCAN_B, 0, stream>>>(chist, boff2, nC);

    // ---- bucket-grouped scatter + in-window local sort (rowptr built here) ----
    k_scatter2<<<nC, 256, ldsHist, stream>>>(erow, ecol, eval, chist, ebuf, nE, nbk, nC);
    k_local_sort2<<<nbk, 256, 0, stream>>>(boff2, ebuf, edges, rowptr, n, nbk);

    // ---- weight prep + GEMM1 ----
    k_prep<<<(F_IN * EDIM + EDIM * 2 * EDIM + 255) / 256, 256, 0, stream>>>(W, catW, Wb, catWb);
    k_gemm1_relu<<<gemmBlocks, 256, 0, stream>>>(feature, Wb, supb, n);

    // ---- SpMMs (bf16 gather, f32 accum) ----
    k_spmm_csr<<<spmmBlocks, 256, 0, stream>>>(rowptr, edges, supb, s1b, n);
    k_spmm_csr<<<spmmBlocks, 256, 0, stream>>>(rowptr, edges, s1b, s2b, n);

    // ---- epilogue GEMM ----
    k_final<<<gemmBlocks, 256, 0, stream>>>(supb, s1b, s2b, out, catWb, catb, b, n);
}

// Round 11
// 432.770 us; speedup vs baseline: 1.2795x; 1.2795x over previous
//
#include <hip/hip_runtime.h>

#define F_IN 256
#define EDIM 128
#define ALPHA 0.2f
#define SCAN_B 1024
#define BM 128
#define CHUNK 8192
#define BROWS 256   // rows per bucket; lrow packs in 8 bits above 17-bit col

typedef unsigned short u16;
typedef unsigned int u32;
typedef __bf16 bf16x8 __attribute__((ext_vector_type(8)));
typedef float f32x4 __attribute__((ext_vector_type(4)));

__device__ __forceinline__ u16 f2b(float f) {
    union { float f; u32 u; } v; v.f = f;
    u32 r = v.u + 0x7FFFu + ((v.u >> 16) & 1u);
    return (u16)(r >> 16);
}
__device__ __forceinline__ float unpack_lo(u32 g) {
    union { u32 u; float f; } v; v.u = g << 16; return v.f;
}
__device__ __forceinline__ float unpack_hi(u32 g) {
    union { u32 u; float f; } v; v.u = g & 0xFFFF0000u; return v.f;
}
__device__ __forceinline__ u32 pack2(float lo, float hi) {
    return ((u32)f2b(hi) << 16) | (u32)f2b(lo);
}

// ---------------- CSR build (no global row-atomics anywhere) ----------------

// One WG per 8192-edge chunk: LDS histogram over buckets -> chist[b][c].
__global__ __launch_bounds__(256) void k_chunk_hist(const int* __restrict__ erow,
                                                    int* __restrict__ chist,
                                                    int nE, int nbk, int nC) {
    extern __shared__ int histo[];
    const int c = blockIdx.x;
    const int t = threadIdx.x;
    for (int i = t; i < nbk; i += 256) histo[i] = 0;
    __syncthreads();
    const int beg = c * CHUNK;
    const int end = min(beg + CHUNK, nE);
    for (int e = beg + t; e < end; e += 256)
        atomicAdd(&histo[erow[e] >> 8], 1);
    __syncthreads();
    for (int i = t; i < nbk; i += 256)
        chist[(size_t)i * nC + c] = histo[i];
}

// One WG per bucket: exclusive scan of its nC chunk-counts; total -> bsum2.
__global__ void k_scan_chunks(int* __restrict__ chist, int* __restrict__ bsum2, int nC) {
    __shared__ int s[SCAN_B];
    const int b = blockIdx.x;
    int t = threadIdx.x;
    int v = (t < nC) ? chist[(size_t)b * nC + t] : 0;
    s[t] = v;
    __syncthreads();
    for (int d = 1; d < SCAN_B; d <<= 1) {
        int add = (t >= d) ? s[t - d] : 0;
        __syncthreads();
        s[t] += add;
        __syncthreads();
    }
    if (t < nC) chist[(size_t)b * nC + t] = s[t] - v;
    if (t == SCAN_B - 1) bsum2[b] = s[t];
}

// Scan bucket totals: boff2 = exclusive, boff2[nbk] = nE.
__global__ void k_scan_bsums(const int* __restrict__ bsum, int* __restrict__ boff, int nb) {
    __shared__ int s[SCAN_B];
    int t = threadIdx.x;
    int v = (t < nb) ? bsum[t] : 0;
    s[t] = v;
    __syncthreads();
    for (int d = 1; d < SCAN_B; d <<= 1) {
        int add = (t >= d) ? s[t - d] : 0;
        __syncthreads();
        s[t] += add;
        __syncthreads();
    }
    if (t < nb) boff[t] = s[t] - v;
    if (t == SCAN_B - 1) boff[nb] = s[t];
}

// One WG per chunk: claim via LDS cursors (chist-local + boff2 folded in),
// write each bucket's edges contiguously into its reserved sub-range.
__global__ __launch_bounds__(256) void k_scatter2(const int* __restrict__ erow,
                                                  const int* __restrict__ ecol,
                                                  const float* __restrict__ eval,
                                                  const int* __restrict__ chist,
                                                  const int* __restrict__ boff2,
                                                  int2* __restrict__ ebuf,
                                                  int nE, int nbk, int nC) {
    extern __shared__ int cur[];
    const int c = blockIdx.x;
    const int t = threadIdx.x;
    for (int i = t; i < nbk; i += 256)
        cur[i] = chist[(size_t)i * nC + c] + boff2[i];
    __syncthreads();
    const int beg = c * CHUNK;
    const int end = min(beg + CHUNK, nE);
    for (int e = beg + t; e < end; e += 256) {
        int r = erow[e];
        int pos = atomicAdd(&cur[r >> 8], 1);
        ebuf[pos] = make_int2(ecol[e] | ((r & (BROWS - 1)) << 17), __float_as_int(eval[e]));
    }
}

// One WG per bucket: LDS row-histogram + scan -> rowptr (coalesced write),
// then cursor-claim pass writes final CSR inside the L2-resident window.
// Last block also zero-pads edges[nE..nE+15].
__global__ __launch_bounds__(256) void k_local_sort2(const int* __restrict__ boff2,
                                                     const int2* __restrict__ ebuf,
                                                     int2* __restrict__ edges,
                                                     int* __restrict__ rowptr,
                                                     int n, int nbk) {
    __shared__ int hist[BROWS];
    __shared__ int s[BROWS];
    const int b = blockIdx.x;
    const int r0 = b * BROWS;
    const int t = threadIdx.x;
    const int beg = boff2[b];
    const int end = boff2[b + 1];
    hist[t] = 0;
    __syncthreads();
    for (int j = beg + t; j < end; j += 256)
        atomicAdd(&hist[(ebuf[j].x >> 17) & (BROWS - 1)], 1);
    __syncthreads();
    int v = hist[t];
    s[t] = v;
    __syncthreads();
    #pragma unroll
    for (int d = 1; d < BROWS; d <<= 1) {
        int add = (t >= d) ? s[t - d] : 0;
        __syncthreads();
        s[t] += add;
        __syncthreads();
    }
    int excl = beg + s[t] - v;
    if (r0 + t < n) rowptr[r0 + t] = excl;
    if (b == nbk - 1 && t == 255) rowptr[n] = end;   // rowptr[n] = nE
    if (b == nbk - 1 && t < 16) edges[end + t] = make_int2(0, 0);  // pad
    hist[t] = excl;                                   // reuse as cursor
    __syncthreads();
    for (int j = beg + t; j < end; j += 256) {
        int2 e = ebuf[j];
        int lrow = (e.x >> 17) & (BROWS - 1);
        int pos = atomicAdd(&hist[lrow], 1);
        edges[pos] = make_int2(e.x & 0x1FFFF, e.y);
    }
}

// ---------------- weight prep ----------------

__global__ void k_prep(const float* __restrict__ W, const float* __restrict__ catW,
                       u16* __restrict__ Wb, u16* __restrict__ catWb) {
    int idx = blockIdx.x * 256 + threadIdx.x;
    if (idx < F_IN * EDIM) {
        int k = idx >> 7;
        int c = idx & 127;
        Wb[c * F_IN + k] = f2b(W[idx]);
    } else {
        int j = idx - F_IN * EDIM;
        if (j < EDIM * 2 * EDIM) catWb[j] = f2b(catW[j]);
    }
}

// ---------------- MFMA GEMMs ----------------

#define LSTRIDE 40

__global__ __launch_bounds__(256) void k_gemm1_relu(const float* __restrict__ feature,
                                                    const u16* __restrict__ Wb,
                                                    u16* __restrict__ supb, int n) {
    __shared__ __align__(16) u16 As[BM][LSTRIDE];
    __shared__ __align__(16) u16 Bs[EDIM][LSTRIDE];
    const int t = threadIdx.x;
    const int r0 = blockIdx.x * BM;
    const int w = t >> 6, lane = t & 63;
    const int wr = w >> 1, wc = w & 1;
    const int lm = lane & 15, kg = lane >> 4;

    f32x4 acc[4][4];
    #pragma unroll
    for (int m = 0; m < 4; ++m)
        #pragma unroll
        for (int nn = 0; nn < 4; ++nn)
            acc[m][nn] = (f32x4){0.f, 0.f, 0.f, 0.f};

    const int srow = t >> 1;
    const int koff = (t & 1) * 16;

    for (int kt = 0; kt < F_IN / 32; ++kt) {
        const int k0 = kt * 32;
        {
            u32 pk[8];
            if (r0 + srow < n) {
                const float* src = feature + (size_t)(r0 + srow) * F_IN + k0 + koff;
                #pragma unroll
                for (int q = 0; q < 4; ++q) {
                    float4 f = *reinterpret_cast<const float4*>(src + q * 4);
                    pk[q * 2 + 0] = pack2(f.x, f.y);
                    pk[q * 2 + 1] = pack2(f.z, f.w);
                }
            } else {
                #pragma unroll
                for (int q = 0; q < 8; ++q) pk[q] = 0;
            }
            uint4* dst = reinterpret_cast<uint4*>(&As[srow][koff]);
            dst[0] = make_uint4(pk[0], pk[1], pk[2], pk[3]);
            dst[1] = make_uint4(pk[4], pk[5], pk[6], pk[7]);
        }
        {
            const uint4* src = reinterpret_cast<const uint4*>(Wb + (size_t)srow * F_IN + k0 + koff);
            uint4* dst = reinterpret_cast<uint4*>(&Bs[srow][koff]);
            dst[0] = src[0];
            dst[1] = src[1];
        }
        __syncthreads();
        #pragma unroll
        for (int m = 0; m < 4; ++m) {
            bf16x8 a = *reinterpret_cast<const bf16x8*>(&As[wr * 64 + m * 16 + lm][kg * 8]);
            #pragma unroll
            for (int nn = 0; nn < 4; ++nn) {
                bf16x8 b = *reinterpret_cast<const bf16x8*>(&Bs[wc * 64 + nn * 16 + lm][kg * 8]);
                acc[m][nn] = __builtin_amdgcn_mfma_f32_16x16x32_bf16(a, b, acc[m][nn], 0, 0, 0);
            }
        }
        __syncthreads();
    }
    #pragma unroll
    for (int m = 0; m < 4; ++m) {
        #pragma unroll
        for (int r = 0; r < 4; ++r) {
            int row = r0 + wr * 64 + m * 16 + kg * 4 + r;
            if (row >= n) continue;
            u16* dst = supb + (size_t)row * EDIM;
            #pragma unroll
            for (int nn = 0; nn < 4; ++nn) {
                int col = wc * 64 + nn * 16 + lm;
                dst[col] = f2b(fmaxf(acc[m][nn][r], 0.f));
            }
        }
    }
}

__global__ __launch_bounds__(256) void k_final(const u16* __restrict__ supb,
                                               const u16* __restrict__ s1b,
                                               const u16* __restrict__ s2b,
                                               float* __restrict__ out,
                                               const u16* __restrict__ catWb,
                                               const float* __restrict__ catb,
                                               const float* __restrict__ bvec, int n) {
    __shared__ __align__(16) u16 As[BM][LSTRIDE];
    __shared__ __align__(16) u16 Bs[EDIM][LSTRIDE];
    const int t = threadIdx.x;
    const int r0 = blockIdx.x * BM;
    const int w = t >> 6, lane = t & 63;
    const int wr = w >> 1, wc = w & 1;
    const int lm = lane & 15, kg = lane >> 4;

    f32x4 acc[4][4];
    #pragma unroll
    for (int m = 0; m < 4; ++m)
        #pragma unroll
        for (int nn = 0; nn < 4; ++nn)
            acc[m][nn] = (f32x4){0.f, 0.f, 0.f, 0.f};

    const int srow = t >> 1;
    const int koff = (t & 1) * 16;

    for (int kt = 0; kt < (2 * EDIM) / 32; ++kt) {
        const int k0 = kt * 32;
        {
            u32 pk[8];
            if (r0 + srow < n) {
                const int kk = k0 + koff;
                const int lo = (kk < EDIM);
                const int kcol = lo ? kk : kk - EDIM;
                size_t off = (size_t)(r0 + srow) * EDIM + kcol;
                const uint4* pa = reinterpret_cast<const uint4*>((lo ? s1b : s2b) + off);
                const uint4* pq = reinterpret_cast<const uint4*>(supb + off);
                uint4 a0 = pa[0], a1 = pa[1];
                uint4 q0 = pq[0], q1 = pq[1];
                const u32 av[8] = {a0.x, a0.y, a0.z, a0.w, a1.x, a1.y, a1.z, a1.w};
                const u32 qv[8] = {q0.x, q0.y, q0.z, q0.w, q1.x, q1.y, q1.z, q1.w};
                const float sgn = lo ? 1.f : -1.f;
                #pragma unroll
                for (int q = 0; q < 8; ++q) {
                    float x = unpack_lo(av[q]) + sgn * unpack_lo(qv[q]);
                    float y = unpack_hi(av[q]) + sgn * unpack_hi(qv[q]);
                    pk[q] = pack2(x, y);
                }
            } else {
                #pragma unroll
                for (int q = 0; q < 8; ++q) pk[q] = 0;
            }
            uint4* dst = reinterpret_cast<uint4*>(&As[srow][koff]);
            dst[0] = make_uint4(pk[0], pk[1], pk[2], pk[3]);
            dst[1] = make_uint4(pk[4], pk[5], pk[6], pk[7]);
        }
        {
            const uint4* src = reinterpret_cast<const uint4*>(catWb + (size_t)srow * (2 * EDIM) + k0 + koff);
            uint4* dst = reinterpret_cast<uint4*>(&Bs[srow][koff]);
            dst[0] = src[0];
            dst[1] = src[1];
        }
        __syncthreads();
        #pragma unroll
        for (int m = 0; m < 4; ++m) {
            bf16x8 a = *reinterpret_cast<const bf16x8*>(&As[wr * 64 + m * 16 + lm][kg * 8]);
            #pragma unroll
            for (int nn = 0; nn < 4; ++nn) {
                bf16x8 b = *reinterpret_cast<const bf16x8*>(&Bs[wc * 64 + nn * 16 + lm][kg * 8]);
                acc[m][nn] = __builtin_amdgcn_mfma_f32_16x16x32_bf16(a, b, acc[m][nn], 0, 0, 0);
            }
        }
        __syncthreads();
    }
    #pragma unroll
    for (int nn = 0; nn < 4; ++nn) {
        int col = wc * 64 + nn * 16 + lm;
        float cbv = catb[col];
        float bbv = bvec[col];
        #pragma unroll
        for (int m = 0; m < 4; ++m) {
            #pragma unroll
            for (int r = 0; r < 4; ++r) {
                int row = r0 + wr * 64 + m * 16 + kg * 4 + r;
                if (row >= n) continue;
                float v = acc[m][nn][r] + cbv;
                v = (v > 0.f ? v : ALPHA * v) + bbv;
                out[(size_t)row * EDIM + col] = v;
            }
        }
    }
}

// y(bf16) = A @ x(bf16): one wave per dest row, lane = 2 cols, f32 accum.
// (round-9 proven form: u32 pair loads, batch-8)
__global__ void k_spmm_csr(const int* __restrict__ rowptr, const int2* __restrict__ edges,
                           const u16* __restrict__ xb, u16* __restrict__ yb, int n) {
    int wid = threadIdx.x >> 6;
    int lane = threadIdx.x & 63;
    int row = blockIdx.x * 4 + wid;
    if (row >= n) return;
    int beg = rowptr[row];
    int end = rowptr[row + 1];
    int c = lane * 2;
    float ax = 0.f, ay = 0.f;
    int j = beg;
    for (; j + 8 <= end; j += 8) {
        int2 ee[8];
        #pragma unroll
        for (int q = 0; q < 8; ++q) ee[q] = edges[j + q];
        u32 gg[8];
        #pragma unroll
        for (int q = 0; q < 8; ++q)
            gg[q] = *reinterpret_cast<const u32*>(xb + (size_t)ee[q].x * EDIM + c);
        #pragma unroll
        for (int q = 0; q < 8; ++q) {
            float v = __int_as_float(ee[q].y);
            ax = fmaf(v, unpack_lo(gg[q]), ax);
            ay = fmaf(v, unpack_hi(gg[q]), ay);
        }
    }
    for (; j < end; ++j) {
        int2 e = edges[j];
        u32 g = *reinterpret_cast<const u32*>(xb + (size_t)e.x * EDIM + c);
        float v = __int_as_float(e.y);
        ax = fmaf(v, unpack_lo(g), ax);
        ay = fmaf(v, unpack_hi(g), ay);
    }
    *reinterpret_cast<u32*>(yb + (size_t)row * EDIM + c) = pack2(ax, ay);
}

extern "C" void kernel_launch(void* const* d_in, const int* in_sizes, int n_in,
                              void* d_out, int out_size, void* d_ws, size_t ws_size,
                              hipStream_t stream) {
    const float* feature = (const float*)d_in[0];
    const int*   erow    = (const int*)d_in[1];
    const int*   ecol    = (const int*)d_in[2];
    const float* eval    = (const float*)d_in[3];
    const float* W       = (const float*)d_in[4];
    const float* b       = (const float*)d_in[5];
    const float* catW    = (const float*)d_in[6];
    const float* catb    = (const float*)d_in[7];
    float* out = (float*)d_out;

    const int n  = in_sizes[0] / F_IN;
    const int nE = in_sizes[1];
    const int nbk = (n + BROWS - 1) / BROWS;        // buckets (<=1024)
    const int nC  = (nE + CHUNK - 1) / CHUNK;       // chunks  (<=1024)

    char* p = (char*)d_ws;
    u16*  supb = (u16*)p;                   p += (size_t)n * EDIM * sizeof(u16);
    u16*  s1b  = (u16*)p;                   p += (size_t)n * EDIM * sizeof(u16);
    u16*  s2b  = (u16*)p;                   p += (size_t)n * EDIM * sizeof(u16);
    p = (char*)(((size_t)p + 15) & ~(size_t)15);
    u16*  Wb   = (u16*)p;                   p += (size_t)F_IN * EDIM * sizeof(u16);
    u16*  catWb = (u16*)p;                  p += (size_t)EDIM * 2 * EDIM * sizeof(u16);
    p = (char*)(((size_t)p + 15) & ~(size_t)15);
    int2* edges = (int2*)p;                 p += (size_t)(nE + 16) * sizeof(int2);
    int2* ebuf  = (int2*)p;                 p += (size_t)nE * sizeof(int2);
    int*  rowptr = (int*)p;                 p += (size_t)(n + 1) * sizeof(int);
    int*  chist  = (int*)p;                 p += (size_t)nbk * nC * sizeof(int);
    int*  bsum2  = (int*)p;                 p += (size_t)nbk * sizeof(int);
    int*  boff2  = (int*)p;                 p += (size_t)(nbk + 1) * sizeof(int);

    const int gemmBlocks = (n + BM - 1) / BM;
    const int spmmBlocks = (n + 3) / 4;
    const size_t ldsHist = (size_t)nbk * sizeof(int);

    // ---- chunk x bucket reservation (atomic-free global ordering) ----
    k_chunk_hist<<<nC, 256, ldsHist, stream>>>(erow, chist, nE, nbk, nC);
    k_scan_chunks<<<nbk, SCAN_B, 0, stream>>>(chist, bsum2, nC);
    k_scan_bsums<<<1, SCAN_B, 0, stream>>>(bsum2, boff2, nbk);

    // ---- bucket-grouped scatter + in-window local sort (rowptr built here) ----
    k_scatter2<<<nC, 256, ldsHist, stream>>>(erow, ecol, eval, chist, boff2, ebuf, nE, nbk, nC);
    k_local_sort2<<<nbk, 256, 0, stream>>>(boff2, ebuf, edges, rowptr, n, nbk);

    // ---- weight prep + GEMM1 ----
    k_prep<<<(F_IN * EDIM + EDIM * 2 * EDIM + 255) / 256, 256, 0, stream>>>(W, catW, Wb, catWb);
    k_gemm1_relu<<<gemmBlocks, 256, 0, stream>>>(feature, Wb, supb, n);

    // ---- SpMMs (bf16 gather, f32 accum) ----
    k_spmm_csr<<<spmmBlocks, 256, 0, stream>>>(rowptr, edges, supb, s1b, n);
    k_spmm_csr<<<spmmBlocks, 256, 0, stream>>>(rowptr, edges, s1b, s2b, n);

    // ---- epilogue GEMM ----
    k_final<<<gemmBlocks, 256, 0, stream>>>(supb, s1b, s2b, out, catWb, catb, b, n);
}

// Round 12
// 407.651 us; speedup vs baseline: 1.3584x; 1.0616x over previous
//
#include <hip/hip_runtime.h>

#define F_IN 256
#define EDIM 128
#define ALPHA 0.2f
#define SCAN_B 1024
#define BM 128
#define CHUNK 8192
#define BROWS 256   // rows per bucket; lrow packs in 8 bits above 17-bit col

typedef unsigned short u16;
typedef unsigned int u32;
typedef __bf16 bf16x8 __attribute__((ext_vector_type(8)));
typedef float f32x4 __attribute__((ext_vector_type(4)));

__device__ __forceinline__ u16 f2b(float f) {
    union { float f; u32 u; } v; v.f = f;
    u32 r = v.u + 0x7FFFu + ((v.u >> 16) & 1u);
    return (u16)(r >> 16);
}
__device__ __forceinline__ float unpack_lo(u32 g) {
    union { u32 u; float f; } v; v.u = g << 16; return v.f;
}
__device__ __forceinline__ float unpack_hi(u32 g) {
    union { u32 u; float f; } v; v.u = g & 0xFFFF0000u; return v.f;
}
__device__ __forceinline__ u32 pack2(float lo, float hi) {
    return ((u32)f2b(hi) << 16) | (u32)f2b(lo);
}

// ---------------- fused: chunk-hist (blocks [0,nC)) + weight prep ----------------

__global__ __launch_bounds__(256) void k_hist_prep(const int* __restrict__ erow,
                                                   int* __restrict__ chist,
                                                   int nE, int nbk, int nC,
                                                   const float* __restrict__ W,
                                                   const float* __restrict__ catW,
                                                   u16* __restrict__ Wb,
                                                   u16* __restrict__ catWb) {
    __shared__ int histo[1024];
    const int t = threadIdx.x;
    if (blockIdx.x < nC) {
        const int c = blockIdx.x;
        for (int i = t; i < nbk; i += 256) histo[i] = 0;
        __syncthreads();
        const int beg = c * CHUNK;
        const int end = min(beg + CHUNK, nE);
        for (int e = beg + t; e < end; e += 256)
            atomicAdd(&histo[erow[e] >> 8], 1);
        __syncthreads();
        for (int i = t; i < nbk; i += 256)
            chist[(size_t)i * nC + c] = histo[i];
    } else {
        int idx = (blockIdx.x - nC) * 256 + t;   // 0..65535
        if (idx < F_IN * EDIM) {
            int k = idx >> 7;
            int c = idx & 127;
            Wb[c * F_IN + k] = f2b(W[idx]);
        } else {
            int j = idx - F_IN * EDIM;
            if (j < EDIM * 2 * EDIM) catWb[j] = f2b(catW[j]);
        }
    }
}

// One WG per bucket: exclusive scan of its nC chunk-counts; total -> bsum2.
__global__ void k_scan_chunks(int* __restrict__ chist, int* __restrict__ bsum2, int nC) {
    __shared__ int s[SCAN_B];
    const int b = blockIdx.x;
    int t = threadIdx.x;
    int v = (t < nC) ? chist[(size_t)b * nC + t] : 0;
    s[t] = v;
    __syncthreads();
    for (int d = 1; d < SCAN_B; d <<= 1) {
        int add = (t >= d) ? s[t - d] : 0;
        __syncthreads();
        s[t] += add;
        __syncthreads();
    }
    if (t < nC) chist[(size_t)b * nC + t] = s[t] - v;
    if (t == SCAN_B - 1) bsum2[b] = s[t];
}

// Scan bucket totals: boff2 = exclusive, boff2[nbk] = nE.
__global__ void k_scan_bsums(const int* __restrict__ bsum, int* __restrict__ boff, int nb) {
    __shared__ int s[SCAN_B];
    int t = threadIdx.x;
    int v = (t < nb) ? bsum[t] : 0;
    s[t] = v;
    __syncthreads();
    for (int d = 1; d < SCAN_B; d <<= 1) {
        int add = (t >= d) ? s[t - d] : 0;
        __syncthreads();
        s[t] += add;
        __syncthreads();
    }
    if (t < nb) boff[t] = s[t] - v;
    if (t == SCAN_B - 1) boff[nb] = s[t];
}

// ---------------- fused: scatter2 (blocks [0,nC)) + MFMA gemm1 ----------------

#define LSTRIDE 40

__global__ __launch_bounds__(256) void k_scatter_gemm(const int* __restrict__ erow,
                                                      const int* __restrict__ ecol,
                                                      const float* __restrict__ eval,
                                                      const int* __restrict__ chist,
                                                      const int* __restrict__ boff2,
                                                      int2* __restrict__ ebuf,
                                                      int nE, int nbk, int nC,
                                                      const float* __restrict__ feature,
                                                      const u16* __restrict__ Wb,
                                                      u16* __restrict__ supb, int n) {
    __shared__ __align__(16) u16 smem[2 * BM * LSTRIDE];   // 20 KB, aliased
    const int t = threadIdx.x;

    if (blockIdx.x < nC) {
        // -------- scatter2 body (cursors in first 1.6 KB of smem) --------
        int* cur = reinterpret_cast<int*>(smem);
        const int c = blockIdx.x;
        for (int i = t; i < nbk; i += 256)
            cur[i] = chist[(size_t)i * nC + c] + boff2[i];
        __syncthreads();
        const int beg = c * CHUNK;
        const int end = min(beg + CHUNK, nE);
        for (int e = beg + t; e < end; e += 256) {
            int r = erow[e];
            int pos = atomicAdd(&cur[r >> 8], 1);
            ebuf[pos] = make_int2(ecol[e] | ((r & (BROWS - 1)) << 17), __float_as_int(eval[e]));
        }
        return;
    }

    // -------- gemm1 body: supb = relu(bf16(feature) @ Wb^T-layout) --------
    u16 (*As)[LSTRIDE] = reinterpret_cast<u16(*)[LSTRIDE]>(smem);
    u16 (*Bs)[LSTRIDE] = reinterpret_cast<u16(*)[LSTRIDE]>(smem + BM * LSTRIDE);
    const int r0 = (blockIdx.x - nC) * BM;
    const int w = t >> 6, lane = t & 63;
    const int wr = w >> 1, wc = w & 1;
    const int lm = lane & 15, kg = lane >> 4;

    f32x4 acc[4][4];
    #pragma unroll
    for (int m = 0; m < 4; ++m)
        #pragma unroll
        for (int nn = 0; nn < 4; ++nn)
            acc[m][nn] = (f32x4){0.f, 0.f, 0.f, 0.f};

    const int srow = t >> 1;
    const int koff = (t & 1) * 16;

    for (int kt = 0; kt < F_IN / 32; ++kt) {
        const int k0 = kt * 32;
        {
            u32 pk[8];
            if (r0 + srow < n) {
                const float* src = feature + (size_t)(r0 + srow) * F_IN + k0 + koff;
                #pragma unroll
                for (int q = 0; q < 4; ++q) {
                    float4 f = *reinterpret_cast<const float4*>(src + q * 4);
                    pk[q * 2 + 0] = pack2(f.x, f.y);
                    pk[q * 2 + 1] = pack2(f.z, f.w);
                }
            } else {
                #pragma unroll
                for (int q = 0; q < 8; ++q) pk[q] = 0;
            }
            uint4* dst = reinterpret_cast<uint4*>(&As[srow][koff]);
            dst[0] = make_uint4(pk[0], pk[1], pk[2], pk[3]);
            dst[1] = make_uint4(pk[4], pk[5], pk[6], pk[7]);
        }
        {
            const uint4* src = reinterpret_cast<const uint4*>(Wb + (size_t)srow * F_IN + k0 + koff);
            uint4* dst = reinterpret_cast<uint4*>(&Bs[srow][koff]);
            dst[0] = src[0];
            dst[1] = src[1];
        }
        __syncthreads();
        #pragma unroll
        for (int m = 0; m < 4; ++m) {
            bf16x8 a = *reinterpret_cast<const bf16x8*>(&As[wr * 64 + m * 16 + lm][kg * 8]);
            #pragma unroll
            for (int nn = 0; nn < 4; ++nn) {
                bf16x8 b = *reinterpret_cast<const bf16x8*>(&Bs[wc * 64 + nn * 16 + lm][kg * 8]);
                acc[m][nn] = __builtin_amdgcn_mfma_f32_16x16x32_bf16(a, b, acc[m][nn], 0, 0, 0);
            }
        }
        __syncthreads();
    }
    #pragma unroll
    for (int m = 0; m < 4; ++m) {
        #pragma unroll
        for (int r = 0; r < 4; ++r) {
            int row = r0 + wr * 64 + m * 16 + kg * 4 + r;
            if (row >= n) continue;
            u16* dst = supb + (size_t)row * EDIM;
            #pragma unroll
            for (int nn = 0; nn < 4; ++nn) {
                int col = wc * 64 + nn * 16 + lm;
                dst[col] = f2b(fmaxf(acc[m][nn][r], 0.f));
            }
        }
    }
}

// One WG per bucket: LDS row-histogram + scan -> rowptr (coalesced write),
// then cursor-claim pass writes final CSR inside the L2-resident window.
// Last block also zero-pads edges[nE..nE+15].
__global__ __launch_bounds__(256) void k_local_sort2(const int* __restrict__ boff2,
                                                     const int2* __restrict__ ebuf,
                                                     int2* __restrict__ edges,
                                                     int* __restrict__ rowptr,
                                                     int n, int nbk) {
    __shared__ int hist[BROWS];
    __shared__ int s[BROWS];
    const int b = blockIdx.x;
    const int r0 = b * BROWS;
    const int t = threadIdx.x;
    const int beg = boff2[b];
    const int end = boff2[b + 1];
    hist[t] = 0;
    __syncthreads();
    for (int j = beg + t; j < end; j += 256)
        atomicAdd(&hist[(ebuf[j].x >> 17) & (BROWS - 1)], 1);
    __syncthreads();
    int v = hist[t];
    s[t] = v;
    __syncthreads();
    #pragma unroll
    for (int d = 1; d < BROWS; d <<= 1) {
        int add = (t >= d) ? s[t - d] : 0;
        __syncthreads();
        s[t] += add;
        __syncthreads();
    }
    int excl = beg + s[t] - v;
    if (r0 + t < n) rowptr[r0 + t] = excl;
    if (b == nbk - 1 && t == 255) rowptr[n] = end;   // rowptr[n] = nE
    if (b == nbk - 1 && t < 16) edges[end + t] = make_int2(0, 0);  // pad
    hist[t] = excl;                                   // reuse as cursor
    __syncthreads();
    for (int j = beg + t; j < end; j += 256) {
        int2 e = ebuf[j];
        int lrow = (e.x >> 17) & (BROWS - 1);
        int pos = atomicAdd(&hist[lrow], 1);
        edges[pos] = make_int2(e.x & 0x1FFFF, e.y);
    }
}

// ---------------- epilogue GEMM ----------------

__global__ __launch_bounds__(256) void k_final(const u16* __restrict__ supb,
                                               const u16* __restrict__ s1b,
                                               const u16* __restrict__ s2b,
                                               float* __restrict__ out,
                                               const u16* __restrict__ catWb,
                                               const float* __restrict__ catb,
                                               const float* __restrict__ bvec, int n) {
    __shared__ __align__(16) u16 As[BM][LSTRIDE];
    __shared__ __align__(16) u16 Bs[EDIM][LSTRIDE];
    const int t = threadIdx.x;
    const int r0 = blockIdx.x * BM;
    const int w = t >> 6, lane = t & 63;
    const int wr = w >> 1, wc = w & 1;
    const int lm = lane & 15, kg = lane >> 4;

    f32x4 acc[4][4];
    #pragma unroll
    for (int m = 0; m < 4; ++m)
        #pragma unroll
        for (int nn = 0; nn < 4; ++nn)
            acc[m][nn] = (f32x4){0.f, 0.f, 0.f, 0.f};

    const int srow = t >> 1;
    const int koff = (t & 1) * 16;

    for (int kt = 0; kt < (2 * EDIM) / 32; ++kt) {
        const int k0 = kt * 32;
        {
            u32 pk[8];
            if (r0 + srow < n) {
                const int kk = k0 + koff;
                const int lo = (kk < EDIM);
                const int kcol = lo ? kk : kk - EDIM;
                size_t off = (size_t)(r0 + srow) * EDIM + kcol;
                const uint4* pa = reinterpret_cast<const uint4*>((lo ? s1b : s2b) + off);
                const uint4* pq = reinterpret_cast<const uint4*>(supb + off);
                uint4 a0 = pa[0], a1 = pa[1];
                uint4 q0 = pq[0], q1 = pq[1];
                const u32 av[8] = {a0.x, a0.y, a0.z, a0.w, a1.x, a1.y, a1.z, a1.w};
                const u32 qv[8] = {q0.x, q0.y, q0.z, q0.w, q1.x, q1.y, q1.z, q1.w};
                const float sgn = lo ? 1.f : -1.f;
                #pragma unroll
                for (int q = 0; q < 8; ++q) {
                    float x = unpack_lo(av[q]) + sgn * unpack_lo(qv[q]);
                    float y = unpack_hi(av[q]) + sgn * unpack_hi(qv[q]);
                    pk[q] = pack2(x, y);
                }
            } else {
                #pragma unroll
                for (int q = 0; q < 8; ++q) pk[q] = 0;
            }
            uint4* dst = reinterpret_cast<uint4*>(&As[srow][koff]);
            dst[0] = make_uint4(pk[0], pk[1], pk[2], pk[3]);
            dst[1] = make_uint4(pk[4], pk[5], pk[6], pk[7]);
        }
        {
            const uint4* src = reinterpret_cast<const uint4*>(catWb + (size_t)srow * (2 * EDIM) + k0 + koff);
            uint4* dst = reinterpret_cast<uint4*>(&Bs[srow][koff]);
            dst[0] = src[0];
            dst[1] = src[1];
        }
        __syncthreads();
        #pragma unroll
        for (int m = 0; m < 4; ++m) {
            bf16x8 a = *reinterpret_cast<const bf16x8*>(&As[wr * 64 + m * 16 + lm][kg * 8]);
            #pragma unroll
            for (int nn = 0; nn < 4; ++nn) {
                bf16x8 b = *reinterpret_cast<const bf16x8*>(&Bs[wc * 64 + nn * 16 + lm][kg * 8]);
                acc[m][nn] = __builtin_amdgcn_mfma_f32_16x16x32_bf16(a, b, acc[m][nn], 0, 0, 0);
            }
        }
        __syncthreads();
    }
    #pragma unroll
    for (int nn = 0; nn < 4; ++nn) {
        int col = wc * 64 + nn * 16 + lm;
        float cbv = catb[col];
        float bbv = bvec[col];
        #pragma unroll
        for (int m = 0; m < 4; ++m) {
            #pragma unroll
            for (int r = 0; r < 4; ++r) {
                int row = r0 + wr * 64 + m * 16 + kg * 4 + r;
                if (row >= n) continue;
                float v = acc[m][nn][r] + cbv;
                v = (v > 0.f ? v : ALPHA * v) + bbv;
                out[(size_t)row * EDIM + col] = v;
            }
        }
    }
}

// y(bf16) = A @ x(bf16): one wave per dest row, lane = 2 cols, f32 accum.
__global__ void k_spmm_csr(const int* __restrict__ rowptr, const int2* __restrict__ edges,
                           const u16* __restrict__ xb, u16* __restrict__ yb, int n) {
    int wid = threadIdx.x >> 6;
    int lane = threadIdx.x & 63;
    int row = blockIdx.x * 4 + wid;
    if (row >= n) return;
    int beg = rowptr[row];
    int end = rowptr[row + 1];
    int c = lane * 2;
    float ax = 0.f, ay = 0.f;
    int j = beg;
    for (; j + 8 <= end; j += 8) {
        int2 ee[8];
        #pragma unroll
        for (int q = 0; q < 8; ++q) ee[q] = edges[j + q];
        u32 gg[8];
        #pragma unroll
        for (int q = 0; q < 8; ++q)
            gg[q] = *reinterpret_cast<const u32*>(xb + (size_t)ee[q].x * EDIM + c);
        #pragma unroll
        for (int q = 0; q < 8; ++q) {
            float v = __int_as_float(ee[q].y);
            ax = fmaf(v, unpack_lo(gg[q]), ax);
            ay = fmaf(v, unpack_hi(gg[q]), ay);
        }
    }
    for (; j < end; ++j) {
        int2 e = edges[j];
        u32 g = *reinterpret_cast<const u32*>(xb + (size_t)e.x * EDIM + c);
        float v = __int_as_float(e.y);
        ax = fmaf(v, unpack_lo(g), ax);
        ay = fmaf(v, unpack_hi(g), ay);
    }
    *reinterpret_cast<u32*>(yb + (size_t)row * EDIM + c) = pack2(ax, ay);
}

extern "C" void kernel_launch(void* const* d_in, const int* in_sizes, int n_in,
                              void* d_out, int out_size, void* d_ws, size_t ws_size,
                              hipStream_t stream) {
    const float* feature = (const float*)d_in[0];
    const int*   erow    = (const int*)d_in[1];
    const int*   ecol    = (const int*)d_in[2];
    const float* eval    = (const float*)d_in[3];
    const float* W       = (const float*)d_in[4];
    const float* b       = (const float*)d_in[5];
    const float* catW    = (const float*)d_in[6];
    const float* catb    = (const float*)d_in[7];
    float* out = (float*)d_out;

    const int n  = in_sizes[0] / F_IN;
    const int nE = in_sizes[1];
    const int nbk = (n + BROWS - 1) / BROWS;        // buckets (<=1024)
    const int nC  = (nE + CHUNK - 1) / CHUNK;       // chunks  (<=1024)

    char* p = (char*)d_ws;
    u16*  supb = (u16*)p;                   p += (size_t)n * EDIM * sizeof(u16);
    u16*  s1b  = (u16*)p;                   p += (size_t)n * EDIM * sizeof(u16);
    u16*  s2b  = (u16*)p;                   p += (size_t)n * EDIM * sizeof(u16);
    p = (char*)(((size_t)p + 15) & ~(size_t)15);
    u16*  Wb   = (u16*)p;                   p += (size_t)F_IN * EDIM * sizeof(u16);
    u16*  catWb = (u16*)p;                  p += (size_t)EDIM * 2 * EDIM * sizeof(u16);
    p = (char*)(((size_t)p + 15) & ~(size_t)15);
    int2* edges = (int2*)p;                 p += (size_t)(nE + 16) * sizeof(int2);
    int2* ebuf  = (int2*)p;                 p += (size_t)nE * sizeof(int2);
    int*  rowptr = (int*)p;                 p += (size_t)(n + 1) * sizeof(int);
    int*  chist  = (int*)p;                 p += (size_t)nbk * nC * sizeof(int);
    int*  bsum2  = (int*)p;                 p += (size_t)nbk * sizeof(int);
    int*  boff2  = (int*)p;                 p += (size_t)(nbk + 1) * sizeof(int);

    const int gemmBlocks = (n + BM - 1) / BM;
    const int spmmBlocks = (n + 3) / 4;
    const int prepBlocks = (F_IN * EDIM + EDIM * 2 * EDIM + 255) / 256;   // 256

    // ---- fused: chunk-hist || weight prep ----
    k_hist_prep<<<nC + prepBlocks, 256, 0, stream>>>(erow, chist, nE, nbk, nC,
                                                     W, catW, Wb, catWb);
    k_scan_chunks<<<nbk, SCAN_B, 0, stream>>>(chist, bsum2, nC);
    k_scan_bsums<<<1, SCAN_B, 0, stream>>>(bsum2, boff2, nbk);

    // ---- fused: bucket-grouped scatter || MFMA gemm1 ----
    k_scatter_gemm<<<nC + gemmBlocks, 256, 0, stream>>>(erow, ecol, eval, chist, boff2,
                                                        ebuf, nE, nbk, nC,
                                                        feature, Wb, supb, n);

    // ---- in-window local sort (rowptr built here) ----
    k_local_sort2<<<nbk, 256, 0, stream>>>(boff2, ebuf, edges, rowptr, n, nbk);

    // ---- SpMMs (bf16 gather, f32 accum) ----
    k_spmm_csr<<<spmmBlocks, 256, 0, stream>>>(rowptr, edges, supb, s1b, n);
    k_spmm_csr<<<spmmBlocks, 256, 0, stream>>>(rowptr, edges, s1b, s2b, n);

    // ---- epilogue GEMM ----
    k_final<<<gemmBlocks, 256, 0, stream>>>(supb, s1b, s2b, out, catWb, catb, b, n);
}